// Round 2
// baseline (4765.822 us; speedup 1.0000x reference)
//
#include <hip/hip_runtime.h>
#include <stdint.h>
#include <stddef.h>

#define HDIM 200
#define FDIM 48
#define ADIM 6
#define BTOT 4096
#define NSTEP 119
#define CTXM1 9  // CONTEXT_FRAMES-1

typedef __attribute__((ext_vector_type(8))) short short8;
typedef __attribute__((ext_vector_type(4))) float floatx4;

// ws layout (bytes)
#define OFF_W1P 0u
#define OFF_W2P 409600u
#define OFF_W3P 1126400u
#define OFF_W4P 1232896u
#define OFF_B1  1254400u
#define OFF_B2  1257600u
#define OFF_B3  1260800u
#define OFF_B4  1261632u

__device__ __forceinline__ unsigned short f2bf(float f) {
  unsigned int u = __float_as_uint(f);
  u += 0x7FFFu + ((u >> 16) & 1u);
  return (unsigned short)(u >> 16);
}
__device__ __forceinline__ float sigm(float x) {
  return 1.0f / (1.0f + __expf(-x));
}
__device__ __forceinline__ float tanh_(float x) {
  return 1.0f - 2.0f / (1.0f + __expf(2.0f * x));
}

// ---------------- weight/bias packing (fp32 in -> bf16 packed) ----------------
// Packed layout per matrix: idx = ((tile*nchunk + chunk)*64 + lane)*8 + j
//   value = Wcat[tile*16 + (lane&15)][chunk*32 + (lane>>4)*8 + j]
// LSTM weight rows interleaved: packed row p = u*4 + gate  <->  source row gate*200 + u
__global__ void actp_pack(
    const float* __restrict__ Wih1, const float* __restrict__ Whh1,
    const float* __restrict__ bih1, const float* __restrict__ bhh1,
    const float* __restrict__ Wih2, const float* __restrict__ Whh2,
    const float* __restrict__ bih2, const float* __restrict__ bhh2,
    const float* __restrict__ fc1w, const float* __restrict__ fc1b,
    const float* __restrict__ fc2w, const float* __restrict__ fc2b,
    unsigned short* __restrict__ W1p, unsigned short* __restrict__ W2p,
    unsigned short* __restrict__ W3p, unsigned short* __restrict__ W4p,
    float* __restrict__ b1, float* __restrict__ b2,
    float* __restrict__ b3, float* __restrict__ b4) {
  int g = blockIdx.x * blockDim.x + threadIdx.x;
  if (g < 25600) {  // W1p: Wcat = [W_ih1(48) | W_hh1(200) | pad8], K=256, 8 chunks
    int lane = g & 63, tc = g >> 6;
    int chunk = tc & 7, tile = tc >> 3;
    int p = tile * 16 + (lane & 15);
    int u = p >> 2, tg = p & 3;
    int srow = tg * 200 + u;
    int kb = chunk * 32 + (lane >> 4) * 8;
    unsigned short* d = W1p + (size_t)g * 8;
#pragma unroll
    for (int j = 0; j < 8; ++j) {
      int k = kb + j;
      float v = 0.f;
      if (k < 48) v = Wih1[srow * 48 + k];
      else if (k < 248) v = Whh1[srow * 200 + (k - 48)];
      d[j] = f2bf(v);
    }
  } else if (g < 70400) {  // W2p: Wcat = [W_ih2(248) | W_hh2(200)], K=448, 14 chunks
    int g2 = g - 25600;
    int lane = g2 & 63, tc = g2 >> 6;
    int chunk = tc % 14, tile = tc / 14;
    int p = tile * 16 + (lane & 15);
    int u = p >> 2, tg = p & 3;
    int srow = tg * 200 + u;
    int kb = chunk * 32 + (lane >> 4) * 8;
    unsigned short* d = W2p + (size_t)g2 * 8;
#pragma unroll
    for (int j = 0; j < 8; ++j) {
      int k = kb + j;
      float v = (k < 248) ? Wih2[srow * 248 + k] : Whh2[srow * 200 + (k - 248)];
      d[j] = f2bf(v);
    }
  } else if (g < 77056) {  // W3p: fc1_w rows padded N->208, K=248->256, 8 chunks
    int g3 = g - 70400;
    int lane = g3 & 63, tc = g3 >> 6;
    int chunk = tc & 7, tile = tc >> 3;
    int p = tile * 16 + (lane & 15);
    int kb = chunk * 32 + (lane >> 4) * 8;
    unsigned short* d = W3p + (size_t)g3 * 8;
#pragma unroll
    for (int j = 0; j < 8; ++j) {
      int k = kb + j;
      float v = (p < 200 && k < 248) ? fc1w[p * 248 + k] : 0.f;
      d[j] = f2bf(v);
    }
  } else if (g < 78400) {  // W4p: fc2_w, N=48, K=200->224, 7 chunks
    int g4 = g - 77056;
    int lane = g4 & 63, tc = g4 >> 6;
    int chunk = tc % 7, tile = tc / 7;
    int p = tile * 16 + (lane & 15);
    int kb = chunk * 32 + (lane >> 4) * 8;
    unsigned short* d = W4p + (size_t)g4 * 8;
#pragma unroll
    for (int j = 0; j < 8; ++j) {
      int k = kb + j;
      float v = (k < 200) ? fc2w[p * 200 + k] : 0.f;
      d[j] = f2bf(v);
    }
  } else if (g < 78400 + 1856) {  // biases (fp32, interleaved gate order)
    int i = g - 78400;
    if (i < 800) {
      int u = i >> 2, tg = i & 3;
      int srow = tg * 200 + u;
      b1[i] = bih1[srow] + bhh1[srow];
    } else if (i < 1600) {
      int p = i - 800;
      int u = p >> 2, tg = p & 3;
      int srow = tg * 200 + u;
      b2[p] = bih2[srow] + bhh2[srow];
    } else if (i < 1808) {
      int p = i - 1600;
      b3[p] = (p < 200) ? fc1b[p] : 0.f;
    } else {
      int p = i - 1808;
      b4[p] = fc2b[p];
    }
  }
}

// ---------------- LSTM in-register elementwise ----------------
// MFMA C layout: col n = lane&15 (gate col), row m = (lane>>4)*4 + r (batch row).
// Gate rows interleaved (p = u*4 + gatetype): the 4 lanes n = 4u'..4u'+3 of a group
// hold i,f,g,o of one hidden unit for the same rows -> gather via 3 shfl_xor.
__device__ __forceinline__ void lstm_ew(floatx4 ac, int mrow0, int u, int tg,
                                        float* __restrict__ cbuf, int cstride,
                                        unsigned short* __restrict__ hbuf, int hstride) {
#pragma unroll
  for (int r = 0; r < 4; ++r) {
    int m = mrow0 + r;
    float x = ac[r];
    float a = (tg == 2) ? tanh_(x) : sigm(x);  // own gate activated
    float a1 = __shfl_xor(a, 1);
    float a2 = __shfl_xor(a, 2);
    float a3 = __shfl_xor(a, 3);
    float gi = (tg == 0) ? a : ((tg == 1) ? a1 : ((tg == 2) ? a2 : a3));
    float gf = (tg == 1) ? a : ((tg == 0) ? a1 : ((tg == 3) ? a2 : a3));
    float gg = (tg == 2) ? a : ((tg == 3) ? a1 : ((tg == 0) ? a2 : a3));
    float go = (tg == 3) ? a : ((tg == 2) ? a1 : ((tg == 1) ? a2 : a3));
    float cp = cbuf[m * cstride + u];
    float cn = gf * cp + gi * gg;
    float hn = go * tanh_(cn);
    if (tg == 0) {
      cbuf[m * cstride + u] = cn;
      hbuf[m * hstride + u] = f2bf(hn);
    }
  }
}

// ---------------- main persistent kernel ----------------
// 128 blocks x 512 threads; block owns rows [32*bid, 32*bid+32), runs all 119 steps.
__global__ __launch_bounds__(512, 2) void actp_main(
    const float* __restrict__ tact,   // T*B*F fp32
    const float* __restrict__ acts,   // T*B*A fp32
    const unsigned short* __restrict__ W1p, const unsigned short* __restrict__ W2p,
    const unsigned short* __restrict__ W3p, const unsigned short* __restrict__ W4p,
    const float* __restrict__ b1, const float* __restrict__ b2,
    const float* __restrict__ b3, const float* __restrict__ b4,
    float* __restrict__ out)          // 110*B*F fp32
{
  __shared__ unsigned short x1[32][264];  // [inp 0:48 | h1 48:248 | pad]
  __shared__ unsigned short x2[32][456];  // [h1 0:200 | tiled 200:248 | h2 248:448 | pad]
  __shared__ unsigned short x3[32][264];  // [h2 0:200 | inp 200:248 | pad]
  __shared__ unsigned short x4[32][232];  // [out3 0:208 | pad]
  __shared__ float c1s[32][208];
  __shared__ float c2s[32][208];

  const int tid = threadIdx.x;
  const int wv = tid >> 6;
  const int lane = tid & 63;
  const int n16 = lane & 15;
  const int qd = lane >> 4;
  const int tg = n16 & 3;
  const int usub = n16 >> 2;
  const int row0 = (int)blockIdx.x * 32;

  // zero-init state + pads (LDS content is undefined; pads must be finite/zero)
  for (int i = tid; i < 32 * 208; i += 512) { (&c1s[0][0])[i] = 0.f; (&c2s[0][0])[i] = 0.f; }
  for (int i = tid; i < 32 * 264; i += 512) { (&x1[0][0])[i] = 0; (&x3[0][0])[i] = 0; }
  for (int i = tid; i < 32 * 456; i += 512) (&x2[0][0])[i] = 0;
  for (int i = tid; i < 32 * 232; i += 512) (&x4[0][0])[i] = 0;
  __syncthreads();

  for (int t = 0; t < NSTEP; ++t) {
    // ---- step-start fills ----
    if (t <= CTXM1) {  // inp = tactiles[t]; for t>9 the FC2 epilogue already wrote inp slots
      for (int i = tid; i < 32 * FDIM; i += 512) {
        int r = i / FDIM, f = i - r * FDIM;
        unsigned short v = f2bf(tact[((size_t)t * BTOT + row0 + r) * FDIM + f]);
        x1[r][f] = v;
        x3[r][HDIM + f] = v;
      }
    }
    for (int i = tid; i < 32 * 12; i += 512) {  // tiled = tile([act_{t+1}|state], 4)
      int r = i / 12, a = i - r * 12;
      float vf = (a < ADIM)
          ? acts[((size_t)(t + 1) * BTOT + row0 + r) * ADIM + a]
          : acts[((size_t)(row0 + r)) * ADIM + (a - ADIM)];
      unsigned short v = f2bf(vf);
      unsigned short* d = &x2[r][HDIM];
      d[a] = v; d[12 + a] = v; d[24 + a] = v; d[36 + a] = v;
    }
    for (int i = tid; i < 32 * HDIM; i += 512) {  // propagate h1,h2 into GEMM slots
      int r = i / HDIM, u = i - r * HDIM;
      x1[r][FDIM + u] = x2[r][u];
      x2[r][248 + u] = x3[r][u];
    }
    __syncthreads();

    // ---- LSTM1: gates1 = [inp|h1] @ W1cat^T + b1 (N=800, K=256) ----
    {
      short8 A0[8], A1[8];
#pragma unroll
      for (int c = 0; c < 8; ++c) {
        A0[c] = *(const short8*)&x1[n16][c * 32 + qd * 8];
        A1[c] = *(const short8*)&x1[16 + n16][c * 32 + qd * 8];
      }
      for (int nt = wv; nt < 50; nt += 8) {
        float bias = b1[nt * 16 + n16];
        floatx4 ac0 = {bias, bias, bias, bias};
        floatx4 ac1 = ac0;
        const short8* wp = (const short8*)W1p + (size_t)(nt * 8) * 64 + lane;
#pragma unroll
        for (int c = 0; c < 8; ++c) {
          short8 bfr = wp[c * 64];
          ac0 = __builtin_amdgcn_mfma_f32_16x16x32_bf16(A0[c], bfr, ac0, 0, 0, 0);
          ac1 = __builtin_amdgcn_mfma_f32_16x16x32_bf16(A1[c], bfr, ac1, 0, 0, 0);
        }
        int u = nt * 4 + usub;
        lstm_ew(ac0, qd * 4, u, tg, &c1s[0][0], 208, &x2[0][0], 456);
        lstm_ew(ac1, 16 + qd * 4, u, tg, &c1s[0][0], 208, &x2[0][0], 456);
      }
    }
    __syncthreads();

    // ---- LSTM2: gates2 = [h1|tiled|h2] @ W2cat^T + b2 (N=800, K=448) ----
    {
      short8 A0[14], A1[14];
#pragma unroll
      for (int c = 0; c < 14; ++c) {
        A0[c] = *(const short8*)&x2[n16][c * 32 + qd * 8];
        A1[c] = *(const short8*)&x2[16 + n16][c * 32 + qd * 8];
      }
      for (int nt = wv; nt < 50; nt += 8) {
        float bias = b2[nt * 16 + n16];
        floatx4 ac0 = {bias, bias, bias, bias};
        floatx4 ac1 = ac0;
        const short8* wp = (const short8*)W2p + (size_t)(nt * 14) * 64 + lane;
#pragma unroll
        for (int c = 0; c < 14; ++c) {
          short8 bfr = wp[c * 64];
          ac0 = __builtin_amdgcn_mfma_f32_16x16x32_bf16(A0[c], bfr, ac0, 0, 0, 0);
          ac1 = __builtin_amdgcn_mfma_f32_16x16x32_bf16(A1[c], bfr, ac1, 0, 0, 0);
        }
        int u = nt * 4 + usub;
        lstm_ew(ac0, qd * 4, u, tg, &c2s[0][0], 208, &x3[0][0], 264);
        lstm_ew(ac1, 16 + qd * 4, u, tg, &c2s[0][0], 208, &x3[0][0], 264);
      }
    }
    __syncthreads();

    // ---- FC1: out3 = tanh([h2|inp] @ fc1_w^T + b3) (N=208 padded, K=256) ----
    {
      short8 A0[8], A1[8];
#pragma unroll
      for (int c = 0; c < 8; ++c) {
        A0[c] = *(const short8*)&x3[n16][c * 32 + qd * 8];
        A1[c] = *(const short8*)&x3[16 + n16][c * 32 + qd * 8];
      }
      for (int nt = wv; nt < 13; nt += 8) {
        float bias = b3[nt * 16 + n16];
        floatx4 ac0 = {bias, bias, bias, bias};
        floatx4 ac1 = ac0;
        const short8* wp = (const short8*)W3p + (size_t)(nt * 8) * 64 + lane;
#pragma unroll
        for (int c = 0; c < 8; ++c) {
          short8 bfr = wp[c * 64];
          ac0 = __builtin_amdgcn_mfma_f32_16x16x32_bf16(A0[c], bfr, ac0, 0, 0, 0);
          ac1 = __builtin_amdgcn_mfma_f32_16x16x32_bf16(A1[c], bfr, ac1, 0, 0, 0);
        }
        int col = nt * 16 + n16;
#pragma unroll
        for (int r = 0; r < 4; ++r) {
          x4[qd * 4 + r][col] = f2bf(tanh_(ac0[r]));
          x4[16 + qd * 4 + r][col] = f2bf(tanh_(ac1[r]));
        }
      }
    }
    __syncthreads();

    // ---- FC2: out4 = tanh(out3 @ fc2_w^T + b4) (N=48, K=224) ----
    if (wv < 6) {  // 6 (ntile, mtile) pairs over waves 0..5
      int nt = wv % 3;
      int mt = wv / 3;
      short8 A[7];
#pragma unroll
      for (int c = 0; c < 7; ++c)
        A[c] = *(const short8*)&x4[mt * 16 + n16][c * 32 + qd * 8];
      float bias = b4[nt * 16 + n16];
      floatx4 ac = {bias, bias, bias, bias};
      const short8* wp = (const short8*)W4p + (size_t)(nt * 7) * 64 + lane;
#pragma unroll
      for (int c = 0; c < 7; ++c)
        ac = __builtin_amdgcn_mfma_f32_16x16x32_bf16(A[c], wp[c * 64], ac, 0, 0, 0);
      int col = nt * 16 + n16;
#pragma unroll
      for (int r = 0; r < 4; ++r) {
        int m = mt * 16 + qd * 4 + r;
        float of = tanh_(ac[r]);
        unsigned short bv = f2bf(of);
        x1[m][col] = bv;          // next step's inp (closed loop)
        x3[m][HDIM + col] = bv;
        if (t >= CTXM1) {
          out[((size_t)(t - CTXM1) * BTOT + row0 + m) * FDIM + col] = of;
        }
      }
    }
    __syncthreads();
  }
}

extern "C" void kernel_launch(void* const* d_in, const int* in_sizes, int n_in,
                              void* d_out, int out_size, void* d_ws, size_t ws_size,
                              hipStream_t stream) {
  const float* tact = (const float*)d_in[0];
  const float* acts = (const float*)d_in[1];
  const float* Wih1 = (const float*)d_in[2];
  const float* Whh1 = (const float*)d_in[3];
  const float* bih1 = (const float*)d_in[4];
  const float* bhh1 = (const float*)d_in[5];
  const float* Wih2 = (const float*)d_in[6];
  const float* Whh2 = (const float*)d_in[7];
  const float* bih2 = (const float*)d_in[8];
  const float* bhh2 = (const float*)d_in[9];
  const float* fc1w = (const float*)d_in[10];
  const float* fc1b = (const float*)d_in[11];
  const float* fc2w = (const float*)d_in[12];
  const float* fc2b = (const float*)d_in[13];

  uint8_t* ws = (uint8_t*)d_ws;
  unsigned short* W1p = (unsigned short*)(ws + OFF_W1P);
  unsigned short* W2p = (unsigned short*)(ws + OFF_W2P);
  unsigned short* W3p = (unsigned short*)(ws + OFF_W3P);
  unsigned short* W4p = (unsigned short*)(ws + OFF_W4P);
  float* b1 = (float*)(ws + OFF_B1);
  float* b2 = (float*)(ws + OFF_B2);
  float* b3 = (float*)(ws + OFF_B3);
  float* b4 = (float*)(ws + OFF_B4);

  hipLaunchKernelGGL(actp_pack, dim3(314), dim3(256), 0, stream,
                     Wih1, Whh1, bih1, bhh1, Wih2, Whh2, bih2, bhh2,
                     fc1w, fc1b, fc2w, fc2b, W1p, W2p, W3p, W4p, b1, b2, b3, b4);
  hipLaunchKernelGGL(actp_main, dim3(128), dim3(512), 0, stream,
                     tact, acts, W1p, W2p, W3p, W4p, b1, b2, b3, b4,
                     (float*)d_out);
}

// Round 3
// 2064.612 us; speedup vs baseline: 2.3083x; 2.3083x over previous
//
#include <hip/hip_runtime.h>
#include <stdint.h>
#include <stddef.h>

#define HDIM 200
#define FDIM 48
#define ADIM 6
#define BTOT 4096
#define NSTEP 119
#define CTXM1 9   // CONTEXT_FRAMES-1
#define MROWS 16  // batch rows per block

typedef __attribute__((ext_vector_type(8))) short short8;
typedef __attribute__((ext_vector_type(4))) float floatx4;

// ws layout (bytes) — gate-major packed weights, N padded to 832 (= 4*208)
#define OFF_W1P 0u        // 52 tiles * 8 chunks * 64 * 8 u16 = 425984 B
#define OFF_W2P 425984u   // 52 * 14 * 64 * 8 u16 = 745472 B
#define OFF_W3P 1171456u  // 13 * 8 * 64 * 8 u16 = 106496 B
#define OFF_W4P 1277952u  // 3 * 7 * 64 * 8 u16 = 21504 B
#define OFF_B1  1299456u  // 832 f32
#define OFF_B2  1302784u  // 832 f32
#define OFF_B3  1306112u  // 208 f32
#define OFF_B4  1306944u  // 48 f32

__device__ __forceinline__ unsigned short f2bf(float f) {
  unsigned int u = __float_as_uint(f);
  u += 0x7FFFu + ((u >> 16) & 1u);
  return (unsigned short)(u >> 16);
}
__device__ __forceinline__ float sigm(float x) {
  return 1.0f / (1.0f + __expf(-x));
}
__device__ __forceinline__ float tanh_(float x) {
  return 1.0f - 2.0f / (1.0f + __expf(2.0f * x));
}

// ---------------- weight/bias packing (fp32 in -> bf16 packed, gate-major) ----------------
// Packed B-fragment layout per matrix: idx = ((tile*nchunk + chunk)*64 + lane)*8 + j
//   value = Wcat[tile*16 + (lane&15)][chunk*32 + (lane>>4)*8 + j]
// LSTM packed row p = gate*208 + u  (gate 0..3 = i,f,g,o; u = hidden unit, pad u>=200 -> 0)
__global__ void actp_pack(
    const float* __restrict__ Wih1, const float* __restrict__ Whh1,
    const float* __restrict__ bih1, const float* __restrict__ bhh1,
    const float* __restrict__ Wih2, const float* __restrict__ Whh2,
    const float* __restrict__ bih2, const float* __restrict__ bhh2,
    const float* __restrict__ fc1w, const float* __restrict__ fc1b,
    const float* __restrict__ fc2w, const float* __restrict__ fc2b,
    unsigned short* __restrict__ W1p, unsigned short* __restrict__ W2p,
    unsigned short* __restrict__ W3p, unsigned short* __restrict__ W4p,
    float* __restrict__ b1, float* __restrict__ b2,
    float* __restrict__ b3, float* __restrict__ b4) {
  int g = blockIdx.x * blockDim.x + threadIdx.x;
  if (g < 26624) {  // W1p: K=256 (inp 48 | h1 200 | pad 8), 8 chunks, 52 tiles
    int lane = g & 63, tc = g >> 6;
    int chunk = tc & 7, tile = tc >> 3;
    int p = tile * 16 + (lane & 15);
    int gate = p / 208, u = p - gate * 208;
    int srow = gate * 200 + u;
    int kb = chunk * 32 + (lane >> 4) * 8;
    unsigned short* d = W1p + (size_t)g * 8;
#pragma unroll
    for (int j = 0; j < 8; ++j) {
      int k = kb + j;
      float v = 0.f;
      if (u < 200) {
        if (k < 48) v = Wih1[srow * 48 + k];
        else if (k < 248) v = Whh1[srow * 200 + (k - 48)];
      }
      d[j] = f2bf(v);
    }
  } else if (g < 73216) {  // W2p: K=448 (h1 200|tiled 48|h2 200), 14 chunks, 52 tiles
    int g2 = g - 26624;
    int lane = g2 & 63, tc = g2 >> 6;
    int chunk = tc % 14, tile = tc / 14;
    int p = tile * 16 + (lane & 15);
    int gate = p / 208, u = p - gate * 208;
    int srow = gate * 200 + u;
    int kb = chunk * 32 + (lane >> 4) * 8;
    unsigned short* d = W2p + (size_t)g2 * 8;
#pragma unroll
    for (int j = 0; j < 8; ++j) {
      int k = kb + j;
      float v = 0.f;
      if (u < 200) v = (k < 248) ? Wih2[srow * 248 + k] : Whh2[srow * 200 + (k - 248)];
      d[j] = f2bf(v);
    }
  } else if (g < 79872) {  // W3p: fc1_w N 200->208, K 248->256, 8 chunks, 13 tiles
    int g3 = g - 73216;
    int lane = g3 & 63, tc = g3 >> 6;
    int chunk = tc & 7, tile = tc >> 3;
    int p = tile * 16 + (lane & 15);
    int kb = chunk * 32 + (lane >> 4) * 8;
    unsigned short* d = W3p + (size_t)g3 * 8;
#pragma unroll
    for (int j = 0; j < 8; ++j) {
      int k = kb + j;
      float v = (p < 200 && k < 248) ? fc1w[p * 248 + k] : 0.f;
      d[j] = f2bf(v);
    }
  } else if (g < 81216) {  // W4p: fc2_w N=48, K 200->224, 7 chunks, 3 tiles
    int g4 = g - 79872;
    int lane = g4 & 63, tc = g4 >> 6;
    int chunk = tc % 7, tile = tc / 7;
    int p = tile * 16 + (lane & 15);
    int kb = chunk * 32 + (lane >> 4) * 8;
    unsigned short* d = W4p + (size_t)g4 * 8;
#pragma unroll
    for (int j = 0; j < 8; ++j) {
      int k = kb + j;
      float v = (k < 200) ? fc2w[p * 200 + k] : 0.f;
      d[j] = f2bf(v);
    }
  } else if (g < 81216 + 1920) {  // biases, gate-major padded
    int i = g - 81216;
    if (i < 832) {
      int gate = i / 208, u = i - gate * 208;
      b1[i] = (u < 200) ? (bih1[gate * 200 + u] + bhh1[gate * 200 + u]) : 0.f;
    } else if (i < 1664) {
      int p = i - 832;
      int gate = p / 208, u = p - gate * 208;
      b2[p] = (u < 200) ? (bih2[gate * 200 + u] + bhh2[gate * 200 + u]) : 0.f;
    } else if (i < 1872) {
      int p = i - 1664;
      b3[p] = (p < 200) ? fc1b[p] : 0.f;
    } else {
      int p = i - 1872;
      b4[p] = fc2b[p];
    }
  }
}

// ---------------- main persistent kernel ----------------
// 256 blocks x 512 threads; block owns rows [16*bid, 16*bid+16), runs all 119 steps.
// Phases per step: A=LSTM1, B=LSTM2, [C=FC1, D=FC2|fills] with EW writing h directly
// into next consumers (no copy phase). x1/x2 double-buffered; x3/x4 single.
__global__ __launch_bounds__(512, 2) void actp_main(
    const float* __restrict__ tact,   // T*B*F fp32
    const float* __restrict__ acts,   // T*B*A fp32
    const unsigned short* __restrict__ W1p, const unsigned short* __restrict__ W2p,
    const unsigned short* __restrict__ W3p, const unsigned short* __restrict__ W4p,
    const float* __restrict__ b1, const float* __restrict__ b2,
    const float* __restrict__ b3, const float* __restrict__ b4,
    float* __restrict__ out)          // 110*B*F fp32
{
  __shared__ unsigned short x1[2][MROWS][264];  // [inp 0:48 | h1 48:248 | pad 248:256]
  __shared__ unsigned short x2[2][MROWS][456];  // [h1 0:200 | tiled 200:248 | h2 248:448]
  __shared__ unsigned short x3[MROWS][264];     // [h2 0:200 | inp 200:248 | pad]
  __shared__ unsigned short x4[MROWS][232];     // [out3 0:208 | pad 208:224]
  __shared__ float c1s[MROWS][228];             // stride 228 = 4 mod 32 -> 2-way (free)
  __shared__ float c2s[MROWS][228];

  const int tid = threadIdx.x;
  const int wv = tid >> 6;
  const int lane = tid & 63;
  const int n16 = lane & 15;
  const int qd = lane >> 4;
  const int row0 = (int)blockIdx.x * MROWS;

  // ---- init: zero everything, fill step-0 inputs ----
  for (int i = tid; i < 2 * MROWS * 264; i += 512) (&x1[0][0][0])[i] = 0;
  for (int i = tid; i < 2 * MROWS * 456; i += 512) (&x2[0][0][0])[i] = 0;
  for (int i = tid; i < MROWS * 264; i += 512) (&x3[0][0])[i] = 0;
  for (int i = tid; i < MROWS * 232; i += 512) (&x4[0][0])[i] = 0;
  for (int i = tid; i < MROWS * 228; i += 512) { (&c1s[0][0])[i] = 0.f; (&c2s[0][0])[i] = 0.f; }
  if (tid < 192) {  // inp(0) = tact[0]
    int r = tid / 12, f0 = (tid % 12) * 4;
    const float* src = &tact[((size_t)(row0 + r)) * FDIM + f0];
#pragma unroll
    for (int j = 0; j < 4; ++j) {
      unsigned short v = f2bf(src[j]);
      x1[0][r][f0 + j] = v;
      x3[r][HDIM + f0 + j] = v;
    }
  } else if (tid < 384) {  // x2[0] tiled = tile([acts[1]|acts[0]], 4)
    int idx = tid - 192;
    int r = idx / 12, a = idx % 12;
    float vf = (a < ADIM) ? acts[((size_t)BTOT + row0 + r) * ADIM + a]
                          : acts[((size_t)(row0 + r)) * ADIM + (a - ADIM)];
    unsigned short v = f2bf(vf);
    unsigned short* d = &x2[0][r][HDIM];
    d[a] = v; d[12 + a] = v; d[24 + a] = v; d[36 + a] = v;
  }
  __syncthreads();

  for (int t = 0; t < NSTEP; ++t) {
    const int cur = t & 1, nxt = cur ^ 1;

    // ---- Phase A: LSTM1  gates = x1 @ W1^T + b1  (N=4x208, K=256) ----
    {
      short8 A0[8];
#pragma unroll
      for (int c = 0; c < 8; ++c) A0[c] = *(const short8*)&x1[cur][n16][c * 32 + qd * 8];
      for (int ut = wv; ut < 13; ut += 8) {
        float bi = b1[(0 * 13 + ut) * 16 + n16];
        float bff = b1[(1 * 13 + ut) * 16 + n16];
        float bg = b1[(2 * 13 + ut) * 16 + n16];
        float bo = b1[(3 * 13 + ut) * 16 + n16];
        floatx4 ai = {bi, bi, bi, bi}, af = {bff, bff, bff, bff};
        floatx4 ag = {bg, bg, bg, bg}, ao = {bo, bo, bo, bo};
        const short8* wi = (const short8*)W1p + (size_t)(0 * 13 + ut) * 8 * 64 + lane;
        const short8* wf = (const short8*)W1p + (size_t)(1 * 13 + ut) * 8 * 64 + lane;
        const short8* wg = (const short8*)W1p + (size_t)(2 * 13 + ut) * 8 * 64 + lane;
        const short8* wo = (const short8*)W1p + (size_t)(3 * 13 + ut) * 8 * 64 + lane;
#pragma unroll
        for (int c = 0; c < 8; ++c) {
          ai = __builtin_amdgcn_mfma_f32_16x16x32_bf16(A0[c], wi[c * 64], ai, 0, 0, 0);
          af = __builtin_amdgcn_mfma_f32_16x16x32_bf16(A0[c], wf[c * 64], af, 0, 0, 0);
          ag = __builtin_amdgcn_mfma_f32_16x16x32_bf16(A0[c], wg[c * 64], ag, 0, 0, 0);
          ao = __builtin_amdgcn_mfma_f32_16x16x32_bf16(A0[c], wo[c * 64], ao, 0, 0, 0);
        }
        int u = ut * 16 + n16;
        bool live = (u < HDIM);
#pragma unroll
        for (int r = 0; r < 4; ++r) {
          int m = qd * 4 + r;
          float gi = sigm(ai[r]), gf = sigm(af[r]);
          float gg = tanh_(ag[r]), go = sigm(ao[r]);
          float cp = c1s[m][u];
          float cn = gf * cp + gi * gg;
          float hn = go * tanh_(cn);
          if (live) {
            c1s[m][u] = cn;
            unsigned short hb = f2bf(hn);
            x2[cur][m][u] = hb;          // LSTM2 input this step
            x1[nxt][m][FDIM + u] = hb;   // LSTM1 input next step
          }
        }
      }
    }
    __syncthreads();

    // ---- Phase B: LSTM2  gates = x2 @ W2^T + b2  (N=4x208, K=448) ----
    {
      short8 A0[14];
#pragma unroll
      for (int c = 0; c < 14; ++c) A0[c] = *(const short8*)&x2[cur][n16][c * 32 + qd * 8];
      for (int ut = wv; ut < 13; ut += 8) {
        float bi = b2[(0 * 13 + ut) * 16 + n16];
        float bff = b2[(1 * 13 + ut) * 16 + n16];
        float bg = b2[(2 * 13 + ut) * 16 + n16];
        float bo = b2[(3 * 13 + ut) * 16 + n16];
        floatx4 ai = {bi, bi, bi, bi}, af = {bff, bff, bff, bff};
        floatx4 ag = {bg, bg, bg, bg}, ao = {bo, bo, bo, bo};
        const short8* wi = (const short8*)W2p + (size_t)(0 * 13 + ut) * 14 * 64 + lane;
        const short8* wf = (const short8*)W2p + (size_t)(1 * 13 + ut) * 14 * 64 + lane;
        const short8* wg = (const short8*)W2p + (size_t)(2 * 13 + ut) * 14 * 64 + lane;
        const short8* wo = (const short8*)W2p + (size_t)(3 * 13 + ut) * 14 * 64 + lane;
#pragma unroll
        for (int c = 0; c < 14; ++c) {
          ai = __builtin_amdgcn_mfma_f32_16x16x32_bf16(A0[c], wi[c * 64], ai, 0, 0, 0);
          af = __builtin_amdgcn_mfma_f32_16x16x32_bf16(A0[c], wf[c * 64], af, 0, 0, 0);
          ag = __builtin_amdgcn_mfma_f32_16x16x32_bf16(A0[c], wg[c * 64], ag, 0, 0, 0);
          ao = __builtin_amdgcn_mfma_f32_16x16x32_bf16(A0[c], wo[c * 64], ao, 0, 0, 0);
        }
        int u = ut * 16 + n16;
        bool live = (u < HDIM);
#pragma unroll
        for (int r = 0; r < 4; ++r) {
          int m = qd * 4 + r;
          float gi = sigm(ai[r]), gf = sigm(af[r]);
          float gg = tanh_(ag[r]), go = sigm(ao[r]);
          float cp = c2s[m][u];
          float cn = gf * cp + gi * gg;
          float hn = go * tanh_(cn);
          if (live) {
            c2s[m][u] = cn;
            unsigned short hb = f2bf(hn);
            x3[m][u] = hb;               // FC1 input this step
            x2[nxt][m][248 + u] = hb;    // LSTM2 input next step
          }
        }
      }
    }
    __syncthreads();

    if (t >= CTXM1) {
      // ---- Phase C: FC1  out3 = tanh(x3 @ fc1_w^T + b3)  (N=208, K=256) ----
      {
        short8 A0[8];
#pragma unroll
        for (int c = 0; c < 8; ++c) A0[c] = *(const short8*)&x3[n16][c * 32 + qd * 8];
        for (int nt = wv; nt < 13; nt += 8) {
          float bb = b3[nt * 16 + n16];
          floatx4 ac = {bb, bb, bb, bb};
          const short8* wp = (const short8*)W3p + (size_t)nt * 8 * 64 + lane;
#pragma unroll
          for (int c = 0; c < 8; ++c)
            ac = __builtin_amdgcn_mfma_f32_16x16x32_bf16(A0[c], wp[c * 64], ac, 0, 0, 0);
          int col = nt * 16 + n16;
#pragma unroll
          for (int r = 0; r < 4; ++r) x4[qd * 4 + r][col] = f2bf(tanh_(ac[r]));
        }
      }
      __syncthreads();
      // ---- Phase D: FC2 on waves 0-2  (N=48, K=224) ----
      if (wv < 3) {
        short8 A0[7];
#pragma unroll
        for (int c = 0; c < 7; ++c) A0[c] = *(const short8*)&x4[n16][c * 32 + qd * 8];
        float bb = b4[wv * 16 + n16];
        floatx4 ac = {bb, bb, bb, bb};
        const short8* wp = (const short8*)W4p + (size_t)wv * 7 * 64 + lane;
#pragma unroll
        for (int c = 0; c < 7; ++c)
          ac = __builtin_amdgcn_mfma_f32_16x16x32_bf16(A0[c], wp[c * 64], ac, 0, 0, 0);
        int col = wv * 16 + n16;
#pragma unroll
        for (int r = 0; r < 4; ++r) {
          int m = qd * 4 + r;
          float of = tanh_(ac[r]);
          out[((size_t)(t - CTXM1) * BTOT + row0 + m) * FDIM + col] = of;
          if (t < NSTEP - 1) {
            unsigned short bv = f2bf(of);
            x1[nxt][m][col] = bv;        // closed-loop inp next step
            x3[m][HDIM + col] = bv;
          }
        }
      }
    } else {
      // ---- Phase D': inp(t+1) = tact[t+1] on waves 0-2 ----
      if (wv < 3) {
        int idx = wv * 64 + lane;  // 0..191
        int r = idx / 12, f0 = (idx % 12) * 4;
        const float* src = &tact[((size_t)(t + 1) * BTOT + row0 + r) * FDIM + f0];
#pragma unroll
        for (int j = 0; j < 4; ++j) {
          unsigned short v = f2bf(src[j]);
          x1[nxt][r][f0 + j] = v;
          x3[r][HDIM + f0 + j] = v;
        }
      }
    }
    // ---- tiled fill for next step (waves 3-5) ----
    if (wv >= 3 && wv < 6 && t < NSTEP - 1) {
      int idx = (wv - 3) * 64 + lane;  // 0..191
      int r = idx / 12, a = idx % 12;
      float vf = (a < ADIM) ? acts[((size_t)(t + 2) * BTOT + row0 + r) * ADIM + a]
                            : acts[((size_t)(row0 + r)) * ADIM + (a - ADIM)];
      unsigned short v = f2bf(vf);
      unsigned short* d = &x2[nxt][r][HDIM];
      d[a] = v; d[12 + a] = v; d[24 + a] = v; d[36 + a] = v;
    }
    __syncthreads();
  }
}

extern "C" void kernel_launch(void* const* d_in, const int* in_sizes, int n_in,
                              void* d_out, int out_size, void* d_ws, size_t ws_size,
                              hipStream_t stream) {
  const float* tact = (const float*)d_in[0];
  const float* acts = (const float*)d_in[1];
  const float* Wih1 = (const float*)d_in[2];
  const float* Whh1 = (const float*)d_in[3];
  const float* bih1 = (const float*)d_in[4];
  const float* bhh1 = (const float*)d_in[5];
  const float* Wih2 = (const float*)d_in[6];
  const float* Whh2 = (const float*)d_in[7];
  const float* bih2 = (const float*)d_in[8];
  const float* bhh2 = (const float*)d_in[9];
  const float* fc1w = (const float*)d_in[10];
  const float* fc1b = (const float*)d_in[11];
  const float* fc2w = (const float*)d_in[12];
  const float* fc2b = (const float*)d_in[13];

  uint8_t* ws = (uint8_t*)d_ws;
  unsigned short* W1p = (unsigned short*)(ws + OFF_W1P);
  unsigned short* W2p = (unsigned short*)(ws + OFF_W2P);
  unsigned short* W3p = (unsigned short*)(ws + OFF_W3P);
  unsigned short* W4p = (unsigned short*)(ws + OFF_W4P);
  float* b1 = (float*)(ws + OFF_B1);
  float* b2 = (float*)(ws + OFF_B2);
  float* b3 = (float*)(ws + OFF_B3);
  float* b4 = (float*)(ws + OFF_B4);

  hipLaunchKernelGGL(actp_pack, dim3(325), dim3(256), 0, stream,
                     Wih1, Whh1, bih1, bhh1, Wih2, Whh2, bih2, bhh2,
                     fc1w, fc1b, fc2w, fc2b, W1p, W2p, W3p, W4p, b1, b2, b3, b4);
  hipLaunchKernelGGL(actp_main, dim3(256), dim3(512), 0, stream,
                     tact, acts, W1p, W2p, W3p, W4p, b1, b2, b3, b4,
                     (float*)d_out);
}